// Round 14
// baseline (669.337 us; speedup 1.0000x reference)
//
#include <hip/hip_runtime.h>

// EncoderDecoderLSTM, round 14.  Base = R12 (640us) + three latency cuts:
//  - MFMA accumulate chains split 4-deep -> 2x2-deep + packed add
//  - merged-reciprocal pointwise: 14 trans insts per 2 elements (was 16)
//  - s_setprio(1) around MFMA clusters (2 independent blocks/CU)
// 512 blocks x 16 rows x 512 threads, 2 blocks/CU, launch_bounds(512,4).

#define TT  336
#define HZN 168
#define NT  512
#define ROWS 16
#define XP  340
#define LN2E 1.44269504088896340736f
#define K2  2.88539008177792681472f   // 2*log2(e)

typedef short s8v __attribute__((ext_vector_type(8)));
typedef float f4v __attribute__((ext_vector_type(4)));
typedef float f2v __attribute__((ext_vector_type(2)));

#define MF(wf, hf, c) __builtin_amdgcn_mfma_f32_16x16x32_bf16((wf), (hf), (c), 0, 0, 0)
#define PRIO1 __builtin_amdgcn_s_setprio(1)
#define PRIO0 __builtin_amdgcn_s_setprio(0)

__device__ __forceinline__ short bf16rne(float f){
  unsigned u = __float_as_uint(f);
  return (short)((u + 0x7fffu + ((u >> 16) & 1u)) >> 16);
}
__device__ __forceinline__ f2v prcp(f2v d){
  return f2v{__builtin_amdgcn_rcpf(d.x), __builtin_amdgcn_rcpf(d.y)};
}
__device__ __forceinline__ f2v pexp2(f2v d){
  return f2v{__builtin_amdgcn_exp2f(d.x), __builtin_amdgcn_exp2f(d.y)};
}

// W fragment, PRE-SCALED by log2(e), permuted m-rows:
// mm -> row (mm&3)*64 + w*8 + 2*(mm>>2) + mt
__device__ __forceinline__ s8v ldW(const float* __restrict__ Wm, int w, int l,
                                   int mt, int kt){
  int mm   = l & 15;
  int grow = (mm & 3)*64 + w*8 + 2*(mm >> 2) + mt;
  int k0   = kt*32 + (l >> 4)*8;
  const float* p = Wm + grow*64 + k0;
  float4 q0 = *(const float4*)(p);
  float4 q1 = *(const float4*)(p + 4);
  s8v v;
  v[0]=bf16rne(q0.x*LN2E); v[1]=bf16rne(q0.y*LN2E);
  v[2]=bf16rne(q0.z*LN2E); v[3]=bf16rne(q0.w*LN2E);
  v[4]=bf16rne(q1.x*LN2E); v[5]=bf16rne(q1.y*LN2E);
  v[6]=bf16rne(q1.z*LN2E); v[7]=bf16rne(q1.w*LN2E);
  return v;
}

// merged-rcp packed pointwise; gates PRE-SCALED by log2(e).
// cn = c/D2 + N1/D1 = (c*D1 + N1*D2) * rcp(D1*D2)
__device__ __forceinline__ void pwise2(f4v aA, f4v aB, f2v& c2,
                                       float& hA, float& hB){
  f2v i2{aA[0], aB[0]}, f2{aA[1], aB[1]}, g2{aA[2], aB[2]}, o2{aA[3], aB[3]};
  f2v ei = pexp2(-i2);
  f2v ef = pexp2(-f2);
  f2v eg = pexp2(g2 + g2);
  f2v eo = pexp2(-o2);
  f2v D1 = (1.f + ei) * (1.f + eg);
  f2v D2 = 1.f + ef;
  f2v N1 = eg - 1.f;
  f2v cn = (c2 * D1 + N1 * D2) * prcp(D1 * D2);
  f2v ec = pexp2(cn * K2);
  f2v h  = (ec - 1.f) * prcp((1.f + eo) * (1.f + ec));
  c2 = cn;
  hA = h.x; hB = h.y;
}

// packed bf16 store of lane's two adjacent h cols
__device__ __forceinline__ void stH2(short* dst, float hA, float hB){
  unsigned pk;
  asm("v_cvt_pk_bf16_f32 %0, %1, %2" : "=v"(pk) : "v"(hA), "v"(hB));
  *(unsigned*)dst = pk;
}

// ---- encoder superphase: L1(t) then (DO_L0 ? L0(t+1) : skip), 1 barrier ----
#define ENC_SUPER(P, t, DO_L0) {                                            \
  const short* h0R  = hS + (P)*2048;                                        \
  short*       h0Wr = hS + ((P)^1)*2048;                                    \
  const short* h1R  = hS + 4096 + (P)*2048;                                 \
  short*       h1Wr = hS + 4096 + ((P)^1)*2048;                             \
  s8v g00 = *(const s8v*)(h0R + lo0), g01 = *(const s8v*)(h0R + lo1);       \
  {                                                                         \
    s8v g10 = *(const s8v*)(h1R + lo0), g11 = *(const s8v*)(h1R + lo1);     \
    f4v aA = bE1a, aB = bE1b;                                               \
    f4v aA2 = {0.f,0.f,0.f,0.f}, aB2 = {0.f,0.f,0.f,0.f};                   \
    PRIO1;                                                                  \
    aA  = MF(Wih1[0][0], g00, aA);  aB  = MF(Wih1[1][0], g00, aB);          \
    aA2 = MF(Wih1[0][1], g01, aA2); aB2 = MF(Wih1[1][1], g01, aB2);         \
    aA  = MF(Whh1[0][0], g10, aA);  aB  = MF(Whh1[1][0], g10, aB);          \
    aA2 = MF(Whh1[0][1], g11, aA2); aB2 = MF(Whh1[1][1], g11, aB2);         \
    PRIO0;                                                                  \
    aA = aA + aA2; aB = aB + aB2;                                           \
    float h1a, h1b;                                                         \
    pwise2(aA, aB, c1s, h1a, h1b);                                          \
    stH2(h1Wr + so, h1a, h1b);                                              \
  }                                                                         \
  if (DO_L0){                                                               \
    float xv = xs[b*XP + (t) + 1];                                          \
    f4v aC = bE0a + wxa*xv;                                                 \
    f4v aD = bE0b + wxb*xv;                                                 \
    PRIO1;                                                                  \
    aC = MF(Whh0[0][0], g00, aC); aD = MF(Whh0[1][0], g00, aD);             \
    aC = MF(Whh0[0][1], g01, aC); aD = MF(Whh0[1][1], g01, aD);             \
    PRIO0;                                                                  \
    float h0a, h0b;                                                         \
    pwise2(aC, aD, c0s, h0a, h0b);                                          \
    stH2(h0Wr + so, h0a, h0b);                                              \
  }                                                                         \
  __syncthreads();                                                          \
}

// ---- decoder step: 2 barriers; h1 fragments loaded once, reused in B ----
#define DEC_STEP(Q, s) {                                                    \
  const short* h0R  = hS + (Q)*2048;                                        \
  short*       h0Wr = hS + ((Q)^1)*2048;                                    \
  const short* h1R  = hS + 4096 + ((Q)^1)*2048;                             \
  short*       h1Wr = hS + 4096 + (Q)*2048;                                 \
  s8v e0 = *(const s8v*)(h1R + lo0), e1 = *(const s8v*)(h1R + lo1);         \
  {                                                                         \
    f4v aA = *(const f4v*)(bD0L + c0*4);                                    \
    f4v aB = *(const f4v*)(bD0L + c0*4 + 4);                                \
    s8v f0 = *(const s8v*)(h0R + lo0), f1 = *(const s8v*)(h0R + lo1);       \
    if ((s) > 0){                                                           \
      f4v aA2 = {0.f,0.f,0.f,0.f}, aB2 = {0.f,0.f,0.f,0.f};                 \
      PRIO1;                                                                \
      aA  = MF(Whh0[0][0], f0, aA);  aB  = MF(Whh0[1][0], f0, aB);          \
      aA2 = MF(Dih0[0][0], e0, aA2); aB2 = MF(Dih0[1][0], e0, aB2);         \
      aA  = MF(Whh0[0][1], f1, aA);  aB  = MF(Whh0[1][1], f1, aB);          \
      aA2 = MF(Dih0[0][1], e1, aA2); aB2 = MF(Dih0[1][1], e1, aB2);         \
      PRIO0;                                                                \
      aA = aA + aA2; aB = aB + aB2;                                         \
    } else {                                                                \
      PRIO1;                                                                \
      aA = MF(Whh0[0][0], f0, aA); aB = MF(Whh0[1][0], f0, aB);             \
      aA = MF(Whh0[0][1], f1, aA); aB = MF(Whh0[1][1], f1, aB);             \
      PRIO0;                                                                \
    }                                                                       \
    float h0a, h0b;                                                         \
    pwise2(aA, aB, c0s, h0a, h0b);                                          \
    stH2(h0Wr + so, h0a, h0b);                                              \
  }                                                                         \
  __syncthreads();                                                          \
  {                                                                         \
    f4v aA = *(const f4v*)(bD1L + c0*4);                                    \
    f4v aB = *(const f4v*)(bD1L + c0*4 + 4);                                \
    f4v aA2 = {0.f,0.f,0.f,0.f}, aB2 = {0.f,0.f,0.f,0.f};                   \
    s8v g0 = *(const s8v*)(h0Wr + lo0), g1 = *(const s8v*)(h0Wr + lo1);     \
    PRIO1;                                                                  \
    aA  = MF(Wih1[0][0], g0, aA);  aB  = MF(Wih1[1][0], g0, aB);            \
    aA2 = MF(Wih1[0][1], g1, aA2); aB2 = MF(Wih1[1][1], g1, aB2);           \
    aA  = MF(Whh1[0][0], e0, aA);  aB  = MF(Whh1[1][0], e0, aB);            \
    aA2 = MF(Whh1[0][1], e1, aA2); aB2 = MF(Whh1[1][1], e1, aB2);           \
    PRIO0;                                                                  \
    aA = aA + aA2; aB = aB + aB2;                                           \
    float h1a, h1b;                                                         \
    pwise2(aA, aB, c1s, h1a, h1b);                                          \
    stH2(h1Wr + so, h1a, h1b);                                              \
    float pr = h1a*fcwA + h1b*fcwB;                                         \
    pr += __shfl_xor(pr, 16); pr += __shfl_xor(pr, 32);                     \
    if (l < 16) fcred[l*9 + w] = pr;                                        \
  }                                                                         \
  __syncthreads();                                                          \
  if (tid < 16){                                                            \
    float sm2 = fcb0;                                                       \
    _Pragma("unroll")                                                       \
    for (int j=0; j<8; j++) sm2 += fcred[tid*9 + j];                        \
    out[(size_t)(brow0 + tid)*HZN + (s)] = sm2;                             \
  }                                                                         \
}

__global__ __launch_bounds__(NT, 4)
void edlstm_kernel(const float* __restrict__ x,
  const float* __restrict__ eWih0, const float* __restrict__ eWhh0,
  const float* __restrict__ ebih0, const float* __restrict__ ebhh0,
  const float* __restrict__ eWih1, const float* __restrict__ eWhh1,
  const float* __restrict__ ebih1, const float* __restrict__ ebhh1,
  const float* __restrict__ dWih0, const float* __restrict__ dWhh0,
  const float* __restrict__ dbih0, const float* __restrict__ dbhh0,
  const float* __restrict__ dWih1, const float* __restrict__ dWhh1,
  const float* __restrict__ dbih1, const float* __restrict__ dbhh1,
  const float* __restrict__ fcW, const float* __restrict__ fcb,
  float* __restrict__ out)
{
  __shared__ float xs[ROWS*XP];
  __shared__ short hS[8192];         // h0[2][2048], h1[2][2048] bf16 swizzled
  __shared__ float fcred[16*9];
  __shared__ float bD0L[256], bD1L[256];

  const int tid = threadIdx.x;
  const int l   = tid & 63;
  const int w   = tid >> 6;
  const int b   = l & 15;
  const int c0  = w*8 + 2*(l >> 4);
  const int brow0 = blockIdx.x * ROWS;

  // loop-invariant swizzled lane offsets (shorts)
  const int lo0 = b*64 + ((((l >> 4)    ) ^ (b & 7)) << 3);
  const int lo1 = b*64 + (((4 + (l >> 4)) ^ (b & 7)) << 3);
  const int so  = b*64 + (((c0 >> 3) ^ (b & 7)) << 3) + (c0 & 7);

  { // zero h buffers
    int4* hz = (int4*)hS;
    #pragma unroll
    for (int k=0; k<2; k++) hz[k*NT + tid] = int4{0,0,0,0};
  }
  #pragma unroll
  for (int k=0; k<3; k++){           // stage x
    int idx = k*NT + tid;
    if (idx < ROWS*84){
      int row = idx / 84;
      int c   = idx - row*84;
      *(float4*)(xs + row*XP + c*4) =
        *(const float4*)(x + (size_t)(brow0+row)*TT + c*4);
    }
  }
  if (tid < 256){                    // decoder bias tables, pre-scaled
    int c = tid >> 2, g = tid & 3;
    int j = g*64 + c;
    bD0L[tid] = (dbih0[j] + dbhh0[j]) * LN2E;
    bD1L[tid] = (dbih1[j] + dbhh1[j]) * LN2E;
  }

  // encoder biases + wx in registers, pre-scaled
  f4v bE0a, bE0b, bE1a, bE1b, wxa, wxb;
  #pragma unroll
  for (int g2=0; g2<4; g2++){
    int j = g2*64 + c0;
    bE0a[g2] = (ebih0[j]   + ebhh0[j])   * LN2E;
    bE0b[g2] = (ebih0[j+1] + ebhh0[j+1]) * LN2E;
    bE1a[g2] = (ebih1[j]   + ebhh1[j])   * LN2E;
    bE1b[g2] = (ebih1[j+1] + ebhh1[j+1]) * LN2E;
    wxa[g2]  = eWih0[j]   * LN2E;
    wxb[g2]  = eWih0[j+1] * LN2E;
  }

  s8v Whh0[2][2], Wih1[2][2], Whh1[2][2];
  #pragma unroll
  for (int mt=0; mt<2; mt++)
    #pragma unroll
    for (int kt=0; kt<2; kt++){
      Whh0[mt][kt] = ldW(eWhh0, w, l, mt, kt);
      Wih1[mt][kt] = ldW(eWih1, w, l, mt, kt);
      Whh1[mt][kt] = ldW(eWhh1, w, l, mt, kt);
    }

  f2v c0s = {0.f, 0.f}, c1s = {0.f, 0.f};
  __syncthreads();

  // ---- encoder prologue: L0(0) = bias + wx*x0 (h0(-1)=0) -> h0buf[1] ----
  {
    float xv = xs[b*XP];
    f4v aA = bE0a + wxa*xv;
    f4v aB = bE0b + wxb*xv;
    float h0a, h0b;
    pwise2(aA, aB, c0s, h0a, h0b);
    stH2(hS + 2048 + so, h0a, h0b);
    __syncthreads();
  }

  // ---- encoder: 336 superphases, 1 barrier each ----
  for (int k=0; k<167; k++){
    ENC_SUPER(1, 2*k,   1);
    ENC_SUPER(0, 2*k+1, 1);
  }
  ENC_SUPER(1, 334, 1);
  ENC_SUPER(0, 335, 0);
  // now: h0(335) in h0buf[0], h1(335) in h1buf[1]

  // ---- decoder weights ----
  s8v Dih0[2][2];
  #pragma unroll
  for (int mt=0; mt<2; mt++)
    #pragma unroll
    for (int kt=0; kt<2; kt++){
      Dih0[mt][kt] = ldW(dWih0, w, l, mt, kt);
      Whh0[mt][kt] = ldW(dWhh0, w, l, mt, kt);
      Wih1[mt][kt] = ldW(dWih1, w, l, mt, kt);
      Whh1[mt][kt] = ldW(dWhh1, w, l, mt, kt);
    }
  const float fcwA = fcW[c0], fcwB = fcW[c0+1], fcb0 = fcb[0];

  // ---- decoder: 168 steps ----
  for (int k=0; k<84; k++){
    DEC_STEP(0, 2*k);
    DEC_STEP(1, 2*k+1);
  }
}

extern "C" void kernel_launch(void* const* d_in, const int* in_sizes, int n_in,
                              void* d_out, int out_size, void* d_ws, size_t ws_size,
                              hipStream_t stream)
{
  (void)in_sizes; (void)n_in; (void)d_ws; (void)ws_size; (void)out_size;
  const float* x     = (const float*)d_in[0];
  const float* eWih0 = (const float*)d_in[1];
  const float* eWhh0 = (const float*)d_in[2];
  const float* ebih0 = (const float*)d_in[3];
  const float* ebhh0 = (const float*)d_in[4];
  const float* eWih1 = (const float*)d_in[5];
  const float* eWhh1 = (const float*)d_in[6];
  const float* ebih1 = (const float*)d_in[7];
  const float* ebhh1 = (const float*)d_in[8];
  const float* dWih0 = (const float*)d_in[9];
  const float* dWhh0 = (const float*)d_in[10];
  const float* dbih0 = (const float*)d_in[11];
  const float* dbhh0 = (const float*)d_in[12];
  const float* dWih1 = (const float*)d_in[13];
  const float* dWhh1 = (const float*)d_in[14];
  const float* dbih1 = (const float*)d_in[15];
  const float* dbhh1 = (const float*)d_in[16];
  const float* fcW   = (const float*)d_in[17];
  const float* fcb   = (const float*)d_in[18];
  float* out = (float*)d_out;

  edlstm_kernel<<<dim3(512), dim3(NT), 0, stream>>>(
      x, eWih0, eWhh0, ebih0, ebhh0, eWih1, eWhh1, ebih1, ebhh1,
      dWih0, dWhh0, dbih0, dbhh0, dWih1, dWhh1, dbih1, dbhh1,
      fcW, fcb, out);
}

// Round 15
// 640.075 us; speedup vs baseline: 1.0457x; 1.0457x over previous
//
#include <hip/hip_runtime.h>

// EncoderDecoderLSTM, round 15.  Base = R12 (640us best) with:
//  - encoder biases/wx moved BACK to LDS (R8-style): frees ~24 VGPRs, the
//    marginal spill source (R11/R12 spilled 39-49MB; R8 with LDS biases 13.6MB)
//  - merged-reciprocal pwise2 kept from R14 (14 trans / 2 elements, no reg cost)
//  - NO chain-split, NO setprio (R14 regression sources)
// 512 blocks x 16 rows x 512 threads, 2 blocks/CU, launch_bounds(512,4).

#define TT  336
#define HZN 168
#define NT  512
#define ROWS 16
#define XP  340
#define LN2E 1.44269504088896340736f
#define K2  2.88539008177792681472f   // 2*log2(e)

typedef short s8v __attribute__((ext_vector_type(8)));
typedef float f4v __attribute__((ext_vector_type(4)));
typedef float f2v __attribute__((ext_vector_type(2)));

#define MF(wf, hf, c) __builtin_amdgcn_mfma_f32_16x16x32_bf16((wf), (hf), (c), 0, 0, 0)

__device__ __forceinline__ short bf16rne(float f){
  unsigned u = __float_as_uint(f);
  return (short)((u + 0x7fffu + ((u >> 16) & 1u)) >> 16);
}
__device__ __forceinline__ f2v prcp(f2v d){
  return f2v{__builtin_amdgcn_rcpf(d.x), __builtin_amdgcn_rcpf(d.y)};
}
__device__ __forceinline__ f2v pexp2(f2v d){
  return f2v{__builtin_amdgcn_exp2f(d.x), __builtin_amdgcn_exp2f(d.y)};
}

// W fragment, PRE-SCALED by log2(e), permuted m-rows:
// mm -> row (mm&3)*64 + w*8 + 2*(mm>>2) + mt
__device__ __forceinline__ s8v ldW(const float* __restrict__ Wm, int w, int l,
                                   int mt, int kt){
  int mm   = l & 15;
  int grow = (mm & 3)*64 + w*8 + 2*(mm >> 2) + mt;
  int k0   = kt*32 + (l >> 4)*8;
  const float* p = Wm + grow*64 + k0;
  float4 q0 = *(const float4*)(p);
  float4 q1 = *(const float4*)(p + 4);
  s8v v;
  v[0]=bf16rne(q0.x*LN2E); v[1]=bf16rne(q0.y*LN2E);
  v[2]=bf16rne(q0.z*LN2E); v[3]=bf16rne(q0.w*LN2E);
  v[4]=bf16rne(q1.x*LN2E); v[5]=bf16rne(q1.y*LN2E);
  v[6]=bf16rne(q1.z*LN2E); v[7]=bf16rne(q1.w*LN2E);
  return v;
}

// merged-rcp packed pointwise; gates PRE-SCALED by log2(e).
// cn = c/D2 + N1/D1 = (c*D1 + N1*D2) * rcp(D1*D2)
__device__ __forceinline__ void pwise2(f4v aA, f4v aB, f2v& c2,
                                       float& hA, float& hB){
  f2v i2{aA[0], aB[0]}, f2{aA[1], aB[1]}, g2{aA[2], aB[2]}, o2{aA[3], aB[3]};
  f2v ei = pexp2(-i2);
  f2v ef = pexp2(-f2);
  f2v eg = pexp2(g2 + g2);
  f2v eo = pexp2(-o2);
  f2v D1 = (1.f + ei) * (1.f + eg);
  f2v D2 = 1.f + ef;
  f2v N1 = eg - 1.f;
  f2v cn = (c2 * D1 + N1 * D2) * prcp(D1 * D2);
  f2v ec = pexp2(cn * K2);
  f2v h  = (ec - 1.f) * prcp((1.f + eo) * (1.f + ec));
  c2 = cn;
  hA = h.x; hB = h.y;
}

// packed bf16 store of lane's two adjacent h cols
__device__ __forceinline__ void stH2(short* dst, float hA, float hB){
  unsigned pk;
  asm("v_cvt_pk_bf16_f32 %0, %1, %2" : "=v"(pk) : "v"(hA), "v"(hB));
  *(unsigned*)dst = pk;
}

// ---- encoder superphase: L1(t) then (DO_L0 ? L0(t+1) : skip), 1 barrier ----
#define ENC_SUPER(P, t, DO_L0) {                                            \
  const short* h0R  = hS + (P)*2048;                                        \
  short*       h0Wr = hS + ((P)^1)*2048;                                    \
  const short* h1R  = hS + 4096 + (P)*2048;                                 \
  short*       h1Wr = hS + 4096 + ((P)^1)*2048;                             \
  s8v g00 = *(const s8v*)(h0R + lo0), g01 = *(const s8v*)(h0R + lo1);       \
  {                                                                         \
    s8v g10 = *(const s8v*)(h1R + lo0), g11 = *(const s8v*)(h1R + lo1);     \
    f4v aA = *(const f4v*)(bE1L + c0*4);                                    \
    f4v aB = *(const f4v*)(bE1L + c0*4 + 4);                                \
    aA = MF(Wih1[0][0], g00, aA); aB = MF(Wih1[1][0], g00, aB);             \
    aA = MF(Wih1[0][1], g01, aA); aB = MF(Wih1[1][1], g01, aB);             \
    aA = MF(Whh1[0][0], g10, aA); aB = MF(Whh1[1][0], g10, aB);             \
    aA = MF(Whh1[0][1], g11, aA); aB = MF(Whh1[1][1], g11, aB);             \
    float h1a, h1b;                                                         \
    pwise2(aA, aB, c1s, h1a, h1b);                                          \
    stH2(h1Wr + so, h1a, h1b);                                              \
  }                                                                         \
  if (DO_L0){                                                               \
    float xv = xs[b*XP + (t) + 1];                                          \
    f4v wxa = *(const f4v*)(wxL + c0*4);                                    \
    f4v wxb = *(const f4v*)(wxL + c0*4 + 4);                                \
    f4v aC = *(const f4v*)(bE0L + c0*4)     + wxa*xv;                       \
    f4v aD = *(const f4v*)(bE0L + c0*4 + 4) + wxb*xv;                       \
    aC = MF(Whh0[0][0], g00, aC); aD = MF(Whh0[1][0], g00, aD);             \
    aC = MF(Whh0[0][1], g01, aC); aD = MF(Whh0[1][1], g01, aD);             \
    float h0a, h0b;                                                         \
    pwise2(aC, aD, c0s, h0a, h0b);                                          \
    stH2(h0Wr + so, h0a, h0b);                                              \
  }                                                                         \
  __syncthreads();                                                          \
}

// ---- decoder step: 2 barriers; h1 fragments loaded once, reused in B ----
#define DEC_STEP(Q, s) {                                                    \
  const short* h0R  = hS + (Q)*2048;                                        \
  short*       h0Wr = hS + ((Q)^1)*2048;                                    \
  const short* h1R  = hS + 4096 + ((Q)^1)*2048;                             \
  short*       h1Wr = hS + 4096 + (Q)*2048;                                 \
  s8v e0 = *(const s8v*)(h1R + lo0), e1 = *(const s8v*)(h1R + lo1);         \
  {                                                                         \
    f4v aA = *(const f4v*)(bD0L + c0*4);                                    \
    f4v aB = *(const f4v*)(bD0L + c0*4 + 4);                                \
    s8v f0 = *(const s8v*)(h0R + lo0), f1 = *(const s8v*)(h0R + lo1);       \
    aA = MF(Whh0[0][0], f0, aA); aB = MF(Whh0[1][0], f0, aB);               \
    aA = MF(Whh0[0][1], f1, aA); aB = MF(Whh0[1][1], f1, aB);               \
    if ((s) > 0){                                                           \
      aA = MF(Dih0[0][0], e0, aA); aB = MF(Dih0[1][0], e0, aB);             \
      aA = MF(Dih0[0][1], e1, aA); aB = MF(Dih0[1][1], e1, aB);             \
    }                                                                       \
    float h0a, h0b;                                                         \
    pwise2(aA, aB, c0s, h0a, h0b);                                          \
    stH2(h0Wr + so, h0a, h0b);                                              \
  }                                                                         \
  __syncthreads();                                                          \
  {                                                                         \
    f4v aA = *(const f4v*)(bD1L + c0*4);                                    \
    f4v aB = *(const f4v*)(bD1L + c0*4 + 4);                                \
    s8v g0 = *(const s8v*)(h0Wr + lo0), g1 = *(const s8v*)(h0Wr + lo1);     \
    aA = MF(Wih1[0][0], g0, aA); aB = MF(Wih1[1][0], g0, aB);               \
    aA = MF(Wih1[0][1], g1, aA); aB = MF(Wih1[1][1], g1, aB);               \
    aA = MF(Whh1[0][0], e0, aA); aB = MF(Whh1[1][0], e0, aB);               \
    aA = MF(Whh1[0][1], e1, aA); aB = MF(Whh1[1][1], e1, aB);               \
    float h1a, h1b;                                                         \
    pwise2(aA, aB, c1s, h1a, h1b);                                          \
    stH2(h1Wr + so, h1a, h1b);                                              \
    float pr = h1a*fcwA + h1b*fcwB;                                         \
    pr += __shfl_xor(pr, 16); pr += __shfl_xor(pr, 32);                     \
    if (l < 16) fcred[l*9 + w] = pr;                                        \
  }                                                                         \
  __syncthreads();                                                          \
  if (tid < 16){                                                            \
    float sm2 = fcb0;                                                       \
    _Pragma("unroll")                                                       \
    for (int j=0; j<8; j++) sm2 += fcred[tid*9 + j];                        \
    out[(size_t)(brow0 + tid)*HZN + (s)] = sm2;                             \
  }                                                                         \
}

__global__ __launch_bounds__(NT, 4)
void edlstm_kernel(const float* __restrict__ x,
  const float* __restrict__ eWih0, const float* __restrict__ eWhh0,
  const float* __restrict__ ebih0, const float* __restrict__ ebhh0,
  const float* __restrict__ eWih1, const float* __restrict__ eWhh1,
  const float* __restrict__ ebih1, const float* __restrict__ ebhh1,
  const float* __restrict__ dWih0, const float* __restrict__ dWhh0,
  const float* __restrict__ dbih0, const float* __restrict__ dbhh0,
  const float* __restrict__ dWih1, const float* __restrict__ dWhh1,
  const float* __restrict__ dbih1, const float* __restrict__ dbhh1,
  const float* __restrict__ fcW, const float* __restrict__ fcb,
  float* __restrict__ out)
{
  __shared__ float xs[ROWS*XP];
  __shared__ short hS[8192];         // h0[2][2048], h1[2][2048] bf16 swizzled
  __shared__ float fcred[16*9];
  __shared__ float bE0L[256], bE1L[256], bD0L[256], bD1L[256], wxL[256];

  const int tid = threadIdx.x;
  const int l   = tid & 63;
  const int w   = tid >> 6;
  const int b   = l & 15;
  const int c0  = w*8 + 2*(l >> 4);
  const int brow0 = blockIdx.x * ROWS;

  // loop-invariant swizzled lane offsets (shorts)
  const int lo0 = b*64 + ((((l >> 4)    ) ^ (b & 7)) << 3);
  const int lo1 = b*64 + (((4 + (l >> 4)) ^ (b & 7)) << 3);
  const int so  = b*64 + (((c0 >> 3) ^ (b & 7)) << 3) + (c0 & 7);

  { // zero h buffers
    int4* hz = (int4*)hS;
    #pragma unroll
    for (int k=0; k<2; k++) hz[k*NT + tid] = int4{0,0,0,0};
  }
  #pragma unroll
  for (int k=0; k<3; k++){           // stage x
    int idx = k*NT + tid;
    if (idx < ROWS*84){
      int row = idx / 84;
      int c   = idx - row*84;
      *(float4*)(xs + row*XP + c*4) =
        *(const float4*)(x + (size_t)(brow0+row)*TT + c*4);
    }
  }
  if (tid < 256){                    // bias/wx tables: [col][gate], pre-scaled
    int c = tid >> 2, g = tid & 3;
    int j = g*64 + c;
    bE0L[tid] = (ebih0[j] + ebhh0[j]) * LN2E;
    bE1L[tid] = (ebih1[j] + ebhh1[j]) * LN2E;
    bD0L[tid] = (dbih0[j] + dbhh0[j]) * LN2E;
    bD1L[tid] = (dbih1[j] + dbhh1[j]) * LN2E;
    wxL[tid]  = eWih0[j] * LN2E;
  }

  s8v Whh0[2][2], Wih1[2][2], Whh1[2][2];
  #pragma unroll
  for (int mt=0; mt<2; mt++)
    #pragma unroll
    for (int kt=0; kt<2; kt++){
      Whh0[mt][kt] = ldW(eWhh0, w, l, mt, kt);
      Wih1[mt][kt] = ldW(eWih1, w, l, mt, kt);
      Whh1[mt][kt] = ldW(eWhh1, w, l, mt, kt);
    }

  f2v c0s = {0.f, 0.f}, c1s = {0.f, 0.f};
  __syncthreads();

  // ---- encoder prologue: L0(0) = bias + wx*x0 (h0(-1)=0) -> h0buf[1] ----
  {
    float xv = xs[b*XP];
    f4v wxa = *(const f4v*)(wxL + c0*4);
    f4v wxb = *(const f4v*)(wxL + c0*4 + 4);
    f4v aA = *(const f4v*)(bE0L + c0*4)     + wxa*xv;
    f4v aB = *(const f4v*)(bE0L + c0*4 + 4) + wxb*xv;
    float h0a, h0b;
    pwise2(aA, aB, c0s, h0a, h0b);
    stH2(hS + 2048 + so, h0a, h0b);
    __syncthreads();
  }

  // ---- encoder: 336 superphases, 1 barrier each ----
  for (int k=0; k<167; k++){
    ENC_SUPER(1, 2*k,   1);
    ENC_SUPER(0, 2*k+1, 1);
  }
  ENC_SUPER(1, 334, 1);
  ENC_SUPER(0, 335, 0);
  // now: h0(335) in h0buf[0], h1(335) in h1buf[1]

  // ---- decoder weights ----
  s8v Dih0[2][2];
  #pragma unroll
  for (int mt=0; mt<2; mt++)
    #pragma unroll
    for (int kt=0; kt<2; kt++){
      Dih0[mt][kt] = ldW(dWih0, w, l, mt, kt);
      Whh0[mt][kt] = ldW(dWhh0, w, l, mt, kt);
      Wih1[mt][kt] = ldW(dWih1, w, l, mt, kt);
      Whh1[mt][kt] = ldW(dWhh1, w, l, mt, kt);
    }
  const float fcwA = fcW[c0], fcwB = fcW[c0+1], fcb0 = fcb[0];

  // ---- decoder: 168 steps ----
  for (int k=0; k<84; k++){
    DEC_STEP(0, 2*k);
    DEC_STEP(1, 2*k+1);
  }
}

extern "C" void kernel_launch(void* const* d_in, const int* in_sizes, int n_in,
                              void* d_out, int out_size, void* d_ws, size_t ws_size,
                              hipStream_t stream)
{
  (void)in_sizes; (void)n_in; (void)d_ws; (void)ws_size; (void)out_size;
  const float* x     = (const float*)d_in[0];
  const float* eWih0 = (const float*)d_in[1];
  const float* eWhh0 = (const float*)d_in[2];
  const float* ebih0 = (const float*)d_in[3];
  const float* ebhh0 = (const float*)d_in[4];
  const float* eWih1 = (const float*)d_in[5];
  const float* eWhh1 = (const float*)d_in[6];
  const float* ebih1 = (const float*)d_in[7];
  const float* ebhh1 = (const float*)d_in[8];
  const float* dWih0 = (const float*)d_in[9];
  const float* dWhh0 = (const float*)d_in[10];
  const float* dbih0 = (const float*)d_in[11];
  const float* dbhh0 = (const float*)d_in[12];
  const float* dWih1 = (const float*)d_in[13];
  const float* dWhh1 = (const float*)d_in[14];
  const float* dbih1 = (const float*)d_in[15];
  const float* dbhh1 = (const float*)d_in[16];
  const float* fcW   = (const float*)d_in[17];
  const float* fcb   = (const float*)d_in[18];
  float* out = (float*)d_out;

  edlstm_kernel<<<dim3(512), dim3(NT), 0, stream>>>(
      x, eWih0, eWhh0, ebih0, ebhh0, eWih1, eWhh1, ebih1, ebhh1,
      dWih0, dWhh0, dbih0, dbhh0, dWih1, dWhh1, dbih1, dbhh1,
      fcW, fcb, out);
}

// Round 16
// 635.407 us; speedup vs baseline: 1.0534x; 1.0073x over previous
//
#include <hip/hip_runtime.h>

// EncoderDecoderLSTM, round 16.  Base = R15 (640us, spill-light) + ONE change:
// encoder superphase de-bursting — issue order becomes
//   {ds_reads -> L1 MFMAs -> L0 MFMAs -> L1 pwise+store -> L0 pwise+store}
// so the L0 matrix work overlaps L1's transcendental chain (matrix pipe and
// trans unit run concurrently instead of serially). No setprio, no chain-split.
// 512 blocks x 16 rows x 512 threads, 2 blocks/CU, launch_bounds(512,4).

#define TT  336
#define HZN 168
#define NT  512
#define ROWS 16
#define XP  340
#define LN2E 1.44269504088896340736f
#define K2  2.88539008177792681472f   // 2*log2(e)

typedef short s8v __attribute__((ext_vector_type(8)));
typedef float f4v __attribute__((ext_vector_type(4)));
typedef float f2v __attribute__((ext_vector_type(2)));

#define MF(wf, hf, c) __builtin_amdgcn_mfma_f32_16x16x32_bf16((wf), (hf), (c), 0, 0, 0)

__device__ __forceinline__ short bf16rne(float f){
  unsigned u = __float_as_uint(f);
  return (short)((u + 0x7fffu + ((u >> 16) & 1u)) >> 16);
}
__device__ __forceinline__ f2v prcp(f2v d){
  return f2v{__builtin_amdgcn_rcpf(d.x), __builtin_amdgcn_rcpf(d.y)};
}
__device__ __forceinline__ f2v pexp2(f2v d){
  return f2v{__builtin_amdgcn_exp2f(d.x), __builtin_amdgcn_exp2f(d.y)};
}

// W fragment, PRE-SCALED by log2(e), permuted m-rows:
// mm -> row (mm&3)*64 + w*8 + 2*(mm>>2) + mt
__device__ __forceinline__ s8v ldW(const float* __restrict__ Wm, int w, int l,
                                   int mt, int kt){
  int mm   = l & 15;
  int grow = (mm & 3)*64 + w*8 + 2*(mm >> 2) + mt;
  int k0   = kt*32 + (l >> 4)*8;
  const float* p = Wm + grow*64 + k0;
  float4 q0 = *(const float4*)(p);
  float4 q1 = *(const float4*)(p + 4);
  s8v v;
  v[0]=bf16rne(q0.x*LN2E); v[1]=bf16rne(q0.y*LN2E);
  v[2]=bf16rne(q0.z*LN2E); v[3]=bf16rne(q0.w*LN2E);
  v[4]=bf16rne(q1.x*LN2E); v[5]=bf16rne(q1.y*LN2E);
  v[6]=bf16rne(q1.z*LN2E); v[7]=bf16rne(q1.w*LN2E);
  return v;
}

// merged-rcp packed pointwise; gates PRE-SCALED by log2(e).
// cn = c/D2 + N1/D1 = (c*D1 + N1*D2) * rcp(D1*D2)
__device__ __forceinline__ void pwise2(f4v aA, f4v aB, f2v& c2,
                                       float& hA, float& hB){
  f2v i2{aA[0], aB[0]}, f2{aA[1], aB[1]}, g2{aA[2], aB[2]}, o2{aA[3], aB[3]};
  f2v ei = pexp2(-i2);
  f2v ef = pexp2(-f2);
  f2v eg = pexp2(g2 + g2);
  f2v eo = pexp2(-o2);
  f2v D1 = (1.f + ei) * (1.f + eg);
  f2v D2 = 1.f + ef;
  f2v N1 = eg - 1.f;
  f2v cn = (c2 * D1 + N1 * D2) * prcp(D1 * D2);
  f2v ec = pexp2(cn * K2);
  f2v h  = (ec - 1.f) * prcp((1.f + eo) * (1.f + ec));
  c2 = cn;
  hA = h.x; hB = h.y;
}

// packed bf16 store of lane's two adjacent h cols
__device__ __forceinline__ void stH2(short* dst, float hA, float hB){
  unsigned pk;
  asm("v_cvt_pk_bf16_f32 %0, %1, %2" : "=v"(pk) : "v"(hA), "v"(hB));
  *(unsigned*)dst = pk;
}

// ---- encoder superphase, DE-BURST order:
//   reads -> L1 MFMAs -> L0 MFMAs -> L1 pwise+store -> L0 pwise+store ----
#define ENC_SUPER(P, t, DO_L0) {                                            \
  const short* h0R  = hS + (P)*2048;                                        \
  short*       h0Wr = hS + ((P)^1)*2048;                                    \
  const short* h1R  = hS + 4096 + (P)*2048;                                 \
  short*       h1Wr = hS + 4096 + ((P)^1)*2048;                             \
  s8v g00 = *(const s8v*)(h0R + lo0), g01 = *(const s8v*)(h0R + lo1);       \
  s8v g10 = *(const s8v*)(h1R + lo0), g11 = *(const s8v*)(h1R + lo1);       \
  f4v aA = *(const f4v*)(bE1L + c0*4);                                      \
  f4v aB = *(const f4v*)(bE1L + c0*4 + 4);                                  \
  f4v aC, aD;                                                               \
  if (DO_L0){                                                               \
    float xv = xs[b*XP + (t) + 1];                                          \
    f4v wxa = *(const f4v*)(wxL + c0*4);                                    \
    f4v wxb = *(const f4v*)(wxL + c0*4 + 4);                                \
    aC = *(const f4v*)(bE0L + c0*4)     + wxa*xv;                           \
    aD = *(const f4v*)(bE0L + c0*4 + 4) + wxb*xv;                           \
  }                                                                         \
  aA = MF(Wih1[0][0], g00, aA); aB = MF(Wih1[1][0], g00, aB);               \
  aA = MF(Wih1[0][1], g01, aA); aB = MF(Wih1[1][1], g01, aB);               \
  aA = MF(Whh1[0][0], g10, aA); aB = MF(Whh1[1][0], g10, aB);               \
  aA = MF(Whh1[0][1], g11, aA); aB = MF(Whh1[1][1], g11, aB);               \
  if (DO_L0){                                                               \
    aC = MF(Whh0[0][0], g00, aC); aD = MF(Whh0[1][0], g00, aD);             \
    aC = MF(Whh0[0][1], g01, aC); aD = MF(Whh0[1][1], g01, aD);             \
  }                                                                         \
  {                                                                         \
    float h1a, h1b;                                                         \
    pwise2(aA, aB, c1s, h1a, h1b);                                          \
    stH2(h1Wr + so, h1a, h1b);                                              \
  }                                                                         \
  if (DO_L0){                                                               \
    float h0a, h0b;                                                         \
    pwise2(aC, aD, c0s, h0a, h0b);                                          \
    stH2(h0Wr + so, h0a, h0b);                                              \
  }                                                                         \
  __syncthreads();                                                          \
}

// ---- decoder step: 2 barriers; h1 fragments loaded once, reused in B ----
#define DEC_STEP(Q, s) {                                                    \
  const short* h0R  = hS + (Q)*2048;                                        \
  short*       h0Wr = hS + ((Q)^1)*2048;                                    \
  const short* h1R  = hS + 4096 + ((Q)^1)*2048;                             \
  short*       h1Wr = hS + 4096 + (Q)*2048;                                 \
  s8v e0 = *(const s8v*)(h1R + lo0), e1 = *(const s8v*)(h1R + lo1);         \
  {                                                                         \
    f4v aA = *(const f4v*)(bD0L + c0*4);                                    \
    f4v aB = *(const f4v*)(bD0L + c0*4 + 4);                                \
    s8v f0 = *(const s8v*)(h0R + lo0), f1 = *(const s8v*)(h0R + lo1);       \
    aA = MF(Whh0[0][0], f0, aA); aB = MF(Whh0[1][0], f0, aB);               \
    aA = MF(Whh0[0][1], f1, aA); aB = MF(Whh0[1][1], f1, aB);               \
    if ((s) > 0){                                                           \
      aA = MF(Dih0[0][0], e0, aA); aB = MF(Dih0[1][0], e0, aB);             \
      aA = MF(Dih0[0][1], e1, aA); aB = MF(Dih0[1][1], e1, aB);             \
    }                                                                       \
    float h0a, h0b;                                                         \
    pwise2(aA, aB, c0s, h0a, h0b);                                          \
    stH2(h0Wr + so, h0a, h0b);                                              \
  }                                                                         \
  __syncthreads();                                                          \
  {                                                                         \
    f4v aA = *(const f4v*)(bD1L + c0*4);                                    \
    f4v aB = *(const f4v*)(bD1L + c0*4 + 4);                                \
    s8v g0 = *(const s8v*)(h0Wr + lo0), g1 = *(const s8v*)(h0Wr + lo1);     \
    aA = MF(Wih1[0][0], g0, aA); aB = MF(Wih1[1][0], g0, aB);               \
    aA = MF(Wih1[0][1], g1, aA); aB = MF(Wih1[1][1], g1, aB);               \
    aA = MF(Whh1[0][0], e0, aA); aB = MF(Whh1[1][0], e0, aB);               \
    aA = MF(Whh1[0][1], e1, aA); aB = MF(Whh1[1][1], e1, aB);               \
    float h1a, h1b;                                                         \
    pwise2(aA, aB, c1s, h1a, h1b);                                          \
    stH2(h1Wr + so, h1a, h1b);                                              \
    float pr = h1a*fcwA + h1b*fcwB;                                         \
    pr += __shfl_xor(pr, 16); pr += __shfl_xor(pr, 32);                     \
    if (l < 16) fcred[l*9 + w] = pr;                                        \
  }                                                                         \
  __syncthreads();                                                          \
  if (tid < 16){                                                            \
    float sm2 = fcb0;                                                       \
    _Pragma("unroll")                                                       \
    for (int j=0; j<8; j++) sm2 += fcred[tid*9 + j];                        \
    out[(size_t)(brow0 + tid)*HZN + (s)] = sm2;                             \
  }                                                                         \
}

__global__ __launch_bounds__(NT, 4)
void edlstm_kernel(const float* __restrict__ x,
  const float* __restrict__ eWih0, const float* __restrict__ eWhh0,
  const float* __restrict__ ebih0, const float* __restrict__ ebhh0,
  const float* __restrict__ eWih1, const float* __restrict__ eWhh1,
  const float* __restrict__ ebih1, const float* __restrict__ ebhh1,
  const float* __restrict__ dWih0, const float* __restrict__ dWhh0,
  const float* __restrict__ dbih0, const float* __restrict__ dbhh0,
  const float* __restrict__ dWih1, const float* __restrict__ dWhh1,
  const float* __restrict__ dbih1, const float* __restrict__ dbhh1,
  const float* __restrict__ fcW, const float* __restrict__ fcb,
  float* __restrict__ out)
{
  __shared__ float xs[ROWS*XP];
  __shared__ short hS[8192];         // h0[2][2048], h1[2][2048] bf16 swizzled
  __shared__ float fcred[16*9];
  __shared__ float bE0L[256], bE1L[256], bD0L[256], bD1L[256], wxL[256];

  const int tid = threadIdx.x;
  const int l   = tid & 63;
  const int w   = tid >> 6;
  const int b   = l & 15;
  const int c0  = w*8 + 2*(l >> 4);
  const int brow0 = blockIdx.x * ROWS;

  // loop-invariant swizzled lane offsets (shorts)
  const int lo0 = b*64 + ((((l >> 4)    ) ^ (b & 7)) << 3);
  const int lo1 = b*64 + (((4 + (l >> 4)) ^ (b & 7)) << 3);
  const int so  = b*64 + (((c0 >> 3) ^ (b & 7)) << 3) + (c0 & 7);

  { // zero h buffers
    int4* hz = (int4*)hS;
    #pragma unroll
    for (int k=0; k<2; k++) hz[k*NT + tid] = int4{0,0,0,0};
  }
  #pragma unroll
  for (int k=0; k<3; k++){           // stage x
    int idx = k*NT + tid;
    if (idx < ROWS*84){
      int row = idx / 84;
      int c   = idx - row*84;
      *(float4*)(xs + row*XP + c*4) =
        *(const float4*)(x + (size_t)(brow0+row)*TT + c*4);
    }
  }
  if (tid < 256){                    // bias/wx tables: [col][gate], pre-scaled
    int c = tid >> 2, g = tid & 3;
    int j = g*64 + c;
    bE0L[tid] = (ebih0[j] + ebhh0[j]) * LN2E;
    bE1L[tid] = (ebih1[j] + ebhh1[j]) * LN2E;
    bD0L[tid] = (dbih0[j] + dbhh0[j]) * LN2E;
    bD1L[tid] = (dbih1[j] + dbhh1[j]) * LN2E;
    wxL[tid]  = eWih0[j] * LN2E;
  }

  s8v Whh0[2][2], Wih1[2][2], Whh1[2][2];
  #pragma unroll
  for (int mt=0; mt<2; mt++)
    #pragma unroll
    for (int kt=0; kt<2; kt++){
      Whh0[mt][kt] = ldW(eWhh0, w, l, mt, kt);
      Wih1[mt][kt] = ldW(eWih1, w, l, mt, kt);
      Whh1[mt][kt] = ldW(eWhh1, w, l, mt, kt);
    }

  f2v c0s = {0.f, 0.f}, c1s = {0.f, 0.f};
  __syncthreads();

  // ---- encoder prologue: L0(0) = bias + wx*x0 (h0(-1)=0) -> h0buf[1] ----
  {
    float xv = xs[b*XP];
    f4v wxa = *(const f4v*)(wxL + c0*4);
    f4v wxb = *(const f4v*)(wxL + c0*4 + 4);
    f4v aA = *(const f4v*)(bE0L + c0*4)     + wxa*xv;
    f4v aB = *(const f4v*)(bE0L + c0*4 + 4) + wxb*xv;
    float h0a, h0b;
    pwise2(aA, aB, c0s, h0a, h0b);
    stH2(hS + 2048 + so, h0a, h0b);
    __syncthreads();
  }

  // ---- encoder: 336 superphases, 1 barrier each ----
  for (int k=0; k<167; k++){
    ENC_SUPER(1, 2*k,   1);
    ENC_SUPER(0, 2*k+1, 1);
  }
  ENC_SUPER(1, 334, 1);
  ENC_SUPER(0, 335, 0);
  // now: h0(335) in h0buf[0], h1(335) in h1buf[1]

  // ---- decoder weights ----
  s8v Dih0[2][2];
  #pragma unroll
  for (int mt=0; mt<2; mt++)
    #pragma unroll
    for (int kt=0; kt<2; kt++){
      Dih0[mt][kt] = ldW(dWih0, w, l, mt, kt);
      Whh0[mt][kt] = ldW(dWhh0, w, l, mt, kt);
      Wih1[mt][kt] = ldW(dWih1, w, l, mt, kt);
      Whh1[mt][kt] = ldW(dWhh1, w, l, mt, kt);
    }
  const float fcwA = fcW[c0], fcwB = fcW[c0+1], fcb0 = fcb[0];

  // ---- decoder: 168 steps ----
  for (int k=0; k<84; k++){
    DEC_STEP(0, 2*k);
    DEC_STEP(1, 2*k+1);
  }
}

extern "C" void kernel_launch(void* const* d_in, const int* in_sizes, int n_in,
                              void* d_out, int out_size, void* d_ws, size_t ws_size,
                              hipStream_t stream)
{
  (void)in_sizes; (void)n_in; (void)d_ws; (void)ws_size; (void)out_size;
  const float* x     = (const float*)d_in[0];
  const float* eWih0 = (const float*)d_in[1];
  const float* eWhh0 = (const float*)d_in[2];
  const float* ebih0 = (const float*)d_in[3];
  const float* ebhh0 = (const float*)d_in[4];
  const float* eWih1 = (const float*)d_in[5];
  const float* eWhh1 = (const float*)d_in[6];
  const float* ebih1 = (const float*)d_in[7];
  const float* ebhh1 = (const float*)d_in[8];
  const float* dWih0 = (const float*)d_in[9];
  const float* dWhh0 = (const float*)d_in[10];
  const float* dbih0 = (const float*)d_in[11];
  const float* dbhh0 = (const float*)d_in[12];
  const float* dWih1 = (const float*)d_in[13];
  const float* dWhh1 = (const float*)d_in[14];
  const float* dbih1 = (const float*)d_in[15];
  const float* dbhh1 = (const float*)d_in[16];
  const float* fcW   = (const float*)d_in[17];
  const float* fcb   = (const float*)d_in[18];
  float* out = (float*)d_out;

  edlstm_kernel<<<dim3(512), dim3(NT), 0, stream>>>(
      x, eWih0, eWhh0, ebih0, ebhh0, eWih1, eWhh1, ebih1, ebhh1,
      dWih0, dWhh0, dbih0, dbhh0, dWih1, dWhh1, dbih1, dbhh1,
      fcW, fcb, out);
}